// Round 1
// baseline (4856.398 us; speedup 1.0000x reference)
//
#include <hip/hip_runtime.h>

// 2-layer GRU, B=512 T=2048 IN=16 H=128 OUT=8.
// Design: 32 WGs x 256 threads (4 waves, 1/SIMD, 512-VGPR budget).
// Each WG owns 16 batch rows for the entire T loop (no grid sync).
// Weights held as f16 MFMA B-fragments in registers (~288 VGPRs/lane).
// mfma_f32_16x16x32_f16; wave w owns gate-col triples (w, 4+w) x (r,z,n)
// so elementwise is fully in-register; h-state lives in registers in C/D
// layout; only h crosses waves via a 4KB permuted-chunk LDS A-layout.

typedef unsigned int  uint;
typedef unsigned short ushort;
typedef _Float16 v8h __attribute__((ext_vector_type(8)));
typedef float    v4f __attribute__((ext_vector_type(4)));

#define Tq   2048
#define INq  16
#define Hq   128
#define OUTq 8
#define BW   16

#define MFMA(a,b,c) __builtin_amdgcn_mfma_f32_16x16x32_f16((a),(b),(c),0,0,0)

__device__ __forceinline__ float sigm(float x){
  return __builtin_amdgcn_rcpf(1.0f + __expf(-x));
}
__device__ __forceinline__ float tanh_f(float x){
  return 1.0f - 2.0f*__builtin_amdgcn_rcpf(__expf(2.0f*x) + 1.0f);
}
__device__ __forceinline__ uint packh2(float lo, float hi){
  _Float16 a = (_Float16)lo, b = (_Float16)hi;
  ushort ua = __builtin_bit_cast(ushort, a);
  ushort ub = __builtin_bit_cast(ushort, b);
  return (uint)ua | ((uint)ub << 16);
}

__global__ __launch_bounds__(256,1) void gru2_kernel(
    const float* __restrict__ x,
    const float* __restrict__ Wih0, const float* __restrict__ Whh0,
    const float* __restrict__ bih0, const float* __restrict__ bhh0,
    const float* __restrict__ Wih1, const float* __restrict__ Whh1,
    const float* __restrict__ bih1, const float* __restrict__ bhh1,
    const float* __restrict__ Wout, const float* __restrict__ bout,
    float* __restrict__ out)
{
  const int tid  = threadIdx.x;
  const int lane = tid & 63;
  const int w    = tid >> 6;      // wave 0..3
  const int col  = lane & 15;     // MFMA col / A row
  const int kg   = lane >> 4;     // 0..3  (A k-group; C/D row-group)
  const int b0   = blockIdx.x * BW;

  // A-fragment LDS: 4 ks-groups x 64 chunks x 8 f16. chunk index permuted:
  // reader lane l -> chunk ((l&3)<<4)|((l>>4)<<2)|((l>>2)&3)  (covers 0..63, linear/conflict-free)
  // writer (b,hidx): ks=hidx>>5, kq=(hidx>>3)&3 -> chunk ((b&3)<<4)|(kq<<2)|(b>>2)
  __shared__ __align__(16) _Float16 hA0[2048];
  __shared__ __align__(16) _Float16 hA1[2048];
  __shared__ __align__(16) _Float16 xA[512];   // K padded 16->32, upper half stays 0

  for (int i = tid; i < 1024; i += 256) ((uint*)hA0)[i] = 0u;
  for (int i = tid; i < 1024; i += 256) ((uint*)hA1)[i] = 0u;
  if (tid < 256) ((uint*)xA)[tid] = 0u;

  // ---------------- weight fragments (registers, f16) ----------------
  v8h Fhh0[2][3][4], Fih1[2][3][4], Fhh1[2][3][4], Fx[2][3], Fo[4];
  float bs_r[2], bs_z[2], bs_nx[2], bs_nh[2];
  float c1_r[2], c1_z[2], c1_nx[2], c1_nh[2];

  #pragma unroll
  for (int tau=0; tau<2; ++tau){
    const int hb = 16*(w + 4*tau) + col;          // hidden index this lane owns
    #pragma unroll
    for (int gg=0; gg<3; ++gg){                   // r,z,n
      const int g = gg*Hq + hb;
      #pragma unroll
      for (int ks=0; ks<4; ++ks){
        const float* p0 = &Whh0[g*Hq + ks*32 + kg*8];
        const float* p1 = &Wih1[g*Hq + ks*32 + kg*8];
        const float* p2 = &Whh1[g*Hq + ks*32 + kg*8];
        v8h a, b, c;
        #pragma unroll
        for (int e=0;e<8;++e){ a[e]=(_Float16)p0[e]; b[e]=(_Float16)p1[e]; c[e]=(_Float16)p2[e]; }
        Fhh0[tau][gg][ks]=a; Fih1[tau][gg][ks]=b; Fhh1[tau][gg][ks]=c;
      }
      v8h vx;
      #pragma unroll
      for (int e=0;e<8;++e) vx[e]=(_Float16)0.f;
      if (kg < 2){
        const float* p = &Wih0[g*INq + kg*8];
        #pragma unroll
        for (int e=0;e<8;++e) vx[e]=(_Float16)p[e];
      }
      Fx[tau][gg]=vx;
    }
    bs_r[tau]  = bih0[hb]        + bhh0[hb];
    bs_z[tau]  = bih0[Hq+hb]     + bhh0[Hq+hb];
    bs_nx[tau] = bih0[2*Hq+hb];
    bs_nh[tau] = bhh0[2*Hq+hb];
    c1_r[tau]  = bih1[hb]        + bhh1[hb];
    c1_z[tau]  = bih1[Hq+hb]     + bhh1[Hq+hb];
    c1_nx[tau] = bih1[2*Hq+hb];
    c1_nh[tau] = bhh1[2*Hq+hb];
  }
  #pragma unroll
  for (int ks=0; ks<4; ++ks){                     // W_out, cols 8..15 zero-padded
    v8h v;
    #pragma unroll
    for (int e=0;e<8;++e) v[e]=(_Float16)0.f;
    if (col < OUTq){
      const float* p = &Wout[col*Hq + ks*32 + kg*8];
      #pragma unroll
      for (int e=0;e<8;++e) v[e]=(_Float16)p[e];
    }
    Fo[ks]=v;
  }
  const float bo_s = (col<OUTq) ? bout[col] : 0.f;

  float h0s[2][4] = {{0,0,0,0},{0,0,0,0}};        // persistent h-state, C/D layout
  float h1s[2][4] = {{0,0,0,0},{0,0,0,0}};

  const int rchunk = ((lane&3)<<4) | (kg<<2) | ((lane>>2)&3);

  // x staging (threads 0..127: row=tid>>3, k-pair=tid&7)
  const int xr = tid>>3, xkp = tid&7;
  float2 xv;
  if (tid < 128){
    xv = *reinterpret_cast<const float2*>(&x[((b0+xr)*Tq + 0)*INq + xkp*2]);
    const int k = xkp*2, kq = (k>>3)&3;
    const int ck = ((xr&3)<<4) | (kq<<2) | (xr>>2);
    ((uint*)xA)[ck*4 + ((k&7)>>1)] = packh2(xv.x, xv.y);
  }
  __syncthreads();

  for (int t=0; t<Tq; ++t){
    const int tn = (t+1 < Tq) ? t+1 : Tq-1;       // prefetch next x
    if (tid < 128)
      xv = *reinterpret_cast<const float2*>(&x[((b0+xr)*Tq + tn)*INq + xkp*2]);

    // ---------------- P1: layer0 gates (hh0 + x), deferred out(t-1) ----------------
    v4f aR[2],aZ[2],aNX[2],aNH[2];
    #pragma unroll
    for (int tau=0;tau<2;++tau){
      aR[tau]  = (v4f){bs_r[tau],bs_r[tau],bs_r[tau],bs_r[tau]};
      aZ[tau]  = (v4f){bs_z[tau],bs_z[tau],bs_z[tau],bs_z[tau]};
      aNX[tau] = (v4f){bs_nx[tau],bs_nx[tau],bs_nx[tau],bs_nx[tau]};
      aNH[tau] = (v4f){bs_nh[tau],bs_nh[tau],bs_nh[tau],bs_nh[tau]};
    }
    {
      v8h a = *reinterpret_cast<const v8h*>(xA + rchunk*8);
      #pragma unroll
      for (int tau=0;tau<2;++tau){
        aR[tau]  = MFMA(a, Fx[tau][0], aR[tau]);
        aZ[tau]  = MFMA(a, Fx[tau][1], aZ[tau]);
        aNX[tau] = MFMA(a, Fx[tau][2], aNX[tau]);
      }
    }
    #pragma unroll
    for (int ks=0;ks<4;++ks){
      v8h a = *reinterpret_cast<const v8h*>(hA0 + ks*512 + rchunk*8);
      #pragma unroll
      for (int tau=0;tau<2;++tau){
        aR[tau]  = MFMA(a, Fhh0[tau][0][ks], aR[tau]);
        aZ[tau]  = MFMA(a, Fhh0[tau][1][ks], aZ[tau]);
        aNH[tau] = MFMA(a, Fhh0[tau][2][ks], aNH[tau]);
      }
    }
    if (w==0 && t>0){                              // output for step t-1 (hA1 still old)
      v4f ao = (v4f){0.f,0.f,0.f,0.f};
      #pragma unroll
      for (int ks=0;ks<4;++ks){
        v8h a = *reinterpret_cast<const v8h*>(hA1 + ks*512 + rchunk*8);
        ao = MFMA(a, Fo[ks], ao);
      }
      if (col < OUTq){
        #pragma unroll
        for (int j=0;j<4;++j)
          out[((b0 + kg*4 + j)*Tq + (t-1))*OUTq + col] = ao[j] + bo_s;
      }
    }
    __syncthreads();

    // ---------------- P2: elementwise-0 (in-register) + write h0 -> hA0 ----------------
    float hn0[2][4];
    #pragma unroll
    for (int tau=0;tau<2;++tau){
      #pragma unroll
      for (int j=0;j<4;++j){
        float r = sigm(aR[tau][j]);
        float z = sigm(aZ[tau][j]);
        float n = tanh_f(aNX[tau][j] + r*aNH[tau][j]);
        float h = n + z*(h0s[tau][j]-n);
        h0s[tau][j]=h; hn0[tau][j]=h;
      }
    }
    {
      uint pk0[4], pk1[4];
      #pragma unroll
      for (int j=0;j<4;++j){
        float o0 = __shfl_xor(hn0[0][j], 1, 64);
        float o1 = __shfl_xor(hn0[1][j], 1, 64);
        float l0 = (col&1)? o0 : hn0[0][j];
        float u0 = (col&1)? hn0[0][j] : o0;
        float l1 = (col&1)? o1 : hn0[1][j];
        float u1 = (col&1)? hn0[1][j] : o1;
        pk0[j]=packh2(l0,u0); pk1[j]=packh2(l1,u1);
      }
      const int tw = col & 1;
      const int hb = 16*(w + 4*tw) + col;
      const int ks = hb >> 5;
      const int kq = (hb>>3)&3;
      const int ep = (col>>1)&3;
      #pragma unroll
      for (int j=0;j<4;++j){
        const int b  = kg*4 + j;
        const int ck = ((b&3)<<4) | (kq<<2) | (b>>2);
        ((uint*)(hA0 + ks*512))[ck*4 + ep] = tw ? pk1[j] : pk0[j];
      }
    }
    __syncthreads();

    // ---------------- P3: layer1 gates (ih1 on new h0, hh1 on old h1) ----------------
    v4f cR[2],cZ[2],cNX[2],cNH[2];
    #pragma unroll
    for (int tau=0;tau<2;++tau){
      cR[tau]  = (v4f){c1_r[tau],c1_r[tau],c1_r[tau],c1_r[tau]};
      cZ[tau]  = (v4f){c1_z[tau],c1_z[tau],c1_z[tau],c1_z[tau]};
      cNX[tau] = (v4f){c1_nx[tau],c1_nx[tau],c1_nx[tau],c1_nx[tau]};
      cNH[tau] = (v4f){c1_nh[tau],c1_nh[tau],c1_nh[tau],c1_nh[tau]};
    }
    #pragma unroll
    for (int ks=0;ks<4;++ks){
      v8h a0 = *reinterpret_cast<const v8h*>(hA0 + ks*512 + rchunk*8);
      v8h a1 = *reinterpret_cast<const v8h*>(hA1 + ks*512 + rchunk*8);
      #pragma unroll
      for (int tau=0;tau<2;++tau){
        cR[tau]  = MFMA(a0, Fih1[tau][0][ks], cR[tau]);
        cZ[tau]  = MFMA(a0, Fih1[tau][1][ks], cZ[tau]);
        cNX[tau] = MFMA(a0, Fih1[tau][2][ks], cNX[tau]);
        cR[tau]  = MFMA(a1, Fhh1[tau][0][ks], cR[tau]);
        cZ[tau]  = MFMA(a1, Fhh1[tau][1][ks], cZ[tau]);
        cNH[tau] = MFMA(a1, Fhh1[tau][2][ks], cNH[tau]);
      }
    }
    __syncthreads();

    // ---------------- P4: elementwise-1 + write h1 -> hA1 + stage x(t+1) ----------------
    float hn1[2][4];
    #pragma unroll
    for (int tau=0;tau<2;++tau){
      #pragma unroll
      for (int j=0;j<4;++j){
        float r = sigm(cR[tau][j]);
        float z = sigm(cZ[tau][j]);
        float n = tanh_f(cNX[tau][j] + r*cNH[tau][j]);
        float h = n + z*(h1s[tau][j]-n);
        h1s[tau][j]=h; hn1[tau][j]=h;
      }
    }
    {
      uint pk0[4], pk1[4];
      #pragma unroll
      for (int j=0;j<4;++j){
        float o0 = __shfl_xor(hn1[0][j], 1, 64);
        float o1 = __shfl_xor(hn1[1][j], 1, 64);
        float l0 = (col&1)? o0 : hn1[0][j];
        float u0 = (col&1)? hn1[0][j] : o0;
        float l1 = (col&1)? o1 : hn1[1][j];
        float u1 = (col&1)? hn1[1][j] : o1;
        pk0[j]=packh2(l0,u0); pk1[j]=packh2(l1,u1);
      }
      const int tw = col & 1;
      const int hb = 16*(w + 4*tw) + col;
      const int ks = hb >> 5;
      const int kq = (hb>>3)&3;
      const int ep = (col>>1)&3;
      #pragma unroll
      for (int j=0;j<4;++j){
        const int b  = kg*4 + j;
        const int ck = ((b&3)<<4) | (kq<<2) | (b>>2);
        ((uint*)(hA1 + ks*512))[ck*4 + ep] = tw ? pk1[j] : pk0[j];
      }
    }
    if (tid < 128){
      const int k = xkp*2, kq2 = (k>>3)&3;
      const int ck = ((xr&3)<<4) | (kq2<<2) | (xr>>2);
      ((uint*)xA)[ck*4 + ((k&7)>>1)] = packh2(xv.x, xv.y);
    }
    __syncthreads();
  }

  // epilogue: output for t = T-1
  if (w==0){
    v4f ao = (v4f){0.f,0.f,0.f,0.f};
    #pragma unroll
    for (int ks=0;ks<4;++ks){
      v8h a = *reinterpret_cast<const v8h*>(hA1 + ks*512 + rchunk*8);
      ao = MFMA(a, Fo[ks], ao);
    }
    if (col < OUTq){
      #pragma unroll
      for (int j=0;j<4;++j)
        out[((b0 + kg*4 + j)*Tq + (Tq-1))*OUTq + col] = ao[j] + bo_s;
    }
  }
}

extern "C" void kernel_launch(void* const* d_in, const int* in_sizes, int n_in,
                              void* d_out, int out_size, void* d_ws, size_t ws_size,
                              hipStream_t stream) {
  const float* x    = (const float*)d_in[0];
  const float* Wih0 = (const float*)d_in[1];
  const float* Whh0 = (const float*)d_in[2];
  const float* bih0 = (const float*)d_in[3];
  const float* bhh0 = (const float*)d_in[4];
  const float* Wih1 = (const float*)d_in[5];
  const float* Whh1 = (const float*)d_in[6];
  const float* bih1 = (const float*)d_in[7];
  const float* bhh1 = (const float*)d_in[8];
  const float* Wout = (const float*)d_in[9];
  const float* bo   = (const float*)d_in[10];
  gru2_kernel<<<dim3(32), dim3(256), 0, stream>>>(
      x, Wih0, Whh0, bih0, bhh0, Wih1, Whh1, bih1, bhh1, Wout, bo,
      (float*)d_out);
}

// Round 2
// 3055.584 us; speedup vs baseline: 1.5894x; 1.5894x over previous
//
#include <hip/hip_runtime.h>

// 2-layer GRU, B=512 T=2048 IN=16 H=128 OUT=8.
// 32 WGs x 512 threads (8 waves, 2/SIMD via launch_bounds(512,2)).
// Wave w owns hidden cols [16w,16w+16) for gates r,z,n of both layers.
// Weights as f16 MFMA B-fragments in registers (~172 VGPR/lane).
// h-state in C/D-layout registers; cross-wave h via double-buffered LDS
// A-fragment layout with XOR bank swizzle chunk=row*4+(kq^((row>>1)&3)).
// 2 barriers/step. x loaded straight to registers (IN=16, k-padded MFMA).

typedef unsigned int uint;
typedef _Float16 v8h __attribute__((ext_vector_type(8)));
typedef float    v4f __attribute__((ext_vector_type(4)));

#define Tq   2048
#define INq  16
#define Hq   128
#define OUTq 8
#define BW   16

#define MFMA(a,b,c) __builtin_amdgcn_mfma_f32_16x16x32_f16((a),(b),(c),0,0,0)

__device__ __forceinline__ float sigm(float x){
  return __builtin_amdgcn_rcpf(1.0f + __expf(-x));
}
__device__ __forceinline__ float tanh_f(float x){
  return 1.0f - 2.0f*__builtin_amdgcn_rcpf(__expf(2.0f*x) + 1.0f);
}
__device__ __forceinline__ int achunk(int row, int kq){
  return row*4 + (kq ^ ((row>>1)&3));   // conflict-free A-frag swizzle
}

__global__ __launch_bounds__(512,2) void gru2_kernel(
    const float* __restrict__ x,
    const float* __restrict__ Wih0, const float* __restrict__ Whh0,
    const float* __restrict__ bih0, const float* __restrict__ bhh0,
    const float* __restrict__ Wih1, const float* __restrict__ Whh1,
    const float* __restrict__ bih1, const float* __restrict__ bhh1,
    const float* __restrict__ Wout, const float* __restrict__ bout,
    float* __restrict__ out)
{
  const int tid  = threadIdx.x;
  const int lane = tid & 63;
  const int w    = tid >> 6;      // wave 0..7
  const int col  = lane & 15;     // MFMA col / A row
  const int bg   = lane >> 4;     // k-group for frags; batch-group for C/D
  const int b0   = blockIdx.x * BW;
  const int hb   = 16*w + col;    // hidden index this lane owns

  // x(0) prefetch issued ASAP, hides under weight prologue
  const float* xrow = &x[(size_t)(b0+col)*Tq*INq];
  float4 xfa, xfb;
  if (bg < 2){
    xfa = *(const float4*)&xrow[0*INq + bg*8 + 0];
    xfb = *(const float4*)&xrow[0*INq + bg*8 + 4];
  }

  __shared__ __align__(16) _Float16 hA0[2][2048];  // [buf][tile*512+chunk*8+e]
  __shared__ __align__(16) _Float16 hA1[2][2048];

  for (int i=tid; i<2048; i+=512) ((uint*)hA0)[i] = 0u;
  for (int i=tid; i<2048; i+=512) ((uint*)hA1)[i] = 0u;

  // ---------------- weight fragments (registers, f16) ----------------
  v8h Fhh0[3][4], Fih1[3][4], Fhh1[3][4], Fx[3], Fo[4];
  #pragma unroll
  for (int g=0; g<3; ++g){
    const int r = g*Hq + hb;
    #pragma unroll
    for (int ks=0; ks<4; ++ks){
      const float* p0 = &Whh0[r*Hq + ks*32 + bg*8];
      const float* p1 = &Wih1[r*Hq + ks*32 + bg*8];
      const float* p2 = &Whh1[r*Hq + ks*32 + bg*8];
      v8h a, b, c;
      #pragma unroll
      for (int e=0;e<8;++e){ a[e]=(_Float16)p0[e]; b[e]=(_Float16)p1[e]; c[e]=(_Float16)p2[e]; }
      Fhh0[g][ks]=a; Fih1[g][ks]=b; Fhh1[g][ks]=c;
    }
    v8h vx;
    #pragma unroll
    for (int e=0;e<8;++e) vx[e]=(_Float16)0.f;
    if (bg < 2){
      const float* p = &Wih0[r*INq + bg*8];
      #pragma unroll
      for (int e=0;e<8;++e) vx[e]=(_Float16)p[e];
    }
    Fx[g]=vx;
  }
  #pragma unroll
  for (int ks=0; ks<4; ++ks){
    v8h v;
    #pragma unroll
    for (int e=0;e<8;++e) v[e]=(_Float16)0.f;
    if (col < OUTq){
      const float* p = &Wout[col*Hq + ks*32 + bg*8];
      #pragma unroll
      for (int e=0;e<8;++e) v[e]=(_Float16)p[e];
    }
    Fo[ks]=v;
  }
  const float bo_s  = (col<OUTq) ? bout[col] : 0.f;
  const float bs_r  = bih0[hb]      + bhh0[hb];
  const float bs_z  = bih0[Hq+hb]   + bhh0[Hq+hb];
  const float bs_nx = bih0[2*Hq+hb];
  const float bs_nh = bhh0[2*Hq+hb];
  const float c1_r  = bih1[hb]      + bhh1[hb];
  const float c1_z  = bih1[Hq+hb]   + bhh1[Hq+hb];
  const float c1_nx = bih1[2*Hq+hb];
  const float c1_nh = bhh1[2*Hq+hb];

  float h0s[4] = {0,0,0,0};          // persistent h-state, C/D layout
  float h1s[4] = {0,0,0,0};

  const int rch    = achunk(col, bg);   // read chunk (row=col, kq=bg)
  const int wtile  = hb >> 5;           // write base for own h column
  const int kq_w   = (hb >> 3) & 3;
  const int elem_w = hb & 7;

  __syncthreads();

  for (int t=0; t<Tq; ++t){
    const int cur = t & 1, prv = cur ^ 1;

    // convert x(t) (loaded in prev phase B / prologue) to f16 A-frag
    v8h ax;
    #pragma unroll
    for (int e=0;e<8;++e) ax[e]=(_Float16)0.f;
    if (bg < 2){
      ax[0]=(_Float16)xfa.x; ax[1]=(_Float16)xfa.y; ax[2]=(_Float16)xfa.z; ax[3]=(_Float16)xfa.w;
      ax[4]=(_Float16)xfb.x; ax[5]=(_Float16)xfb.y; ax[6]=(_Float16)xfb.z; ax[7]=(_Float16)xfb.w;
    }

    // ---------------- phase A: layer-0 gates ----------------
    v4f aR  = {bs_r, bs_r, bs_r, bs_r};
    v4f aZ  = {bs_z, bs_z, bs_z, bs_z};
    v4f aNX = {bs_nx,bs_nx,bs_nx,bs_nx};
    v4f aNH = {bs_nh,bs_nh,bs_nh,bs_nh};
    aR  = MFMA(ax, Fx[0], aR);
    aZ  = MFMA(ax, Fx[1], aZ);
    aNX = MFMA(ax, Fx[2], aNX);
    #pragma unroll
    for (int ks=0;ks<4;++ks){
      v8h a = *(const v8h*)&hA0[prv][ks*512 + rch*8];
      aR  = MFMA(a, Fhh0[0][ks], aR);
      aZ  = MFMA(a, Fhh0[1][ks], aZ);
      aNH = MFMA(a, Fhh0[2][ks], aNH);
    }
    // out-projection (reads+MFMA before barrier; stores after). Even t:
    // wave0 -> out(t-2) from hA1[cur], wave1 -> out(t-1) from hA1[prv].
    const bool doout = ((t&1)==0) && (t>=2) && (w<2);
    v4f ao;
    if (doout){
      const _Float16* hsrc = (w==0) ? &hA1[cur][0] : &hA1[prv][0];
      ao = (v4f){0.f,0.f,0.f,0.f};
      #pragma unroll
      for (int ks=0;ks<4;++ks){
        v8h a = *(const v8h*)&hsrc[ks*512 + rch*8];
        ao = MFMA(a, Fo[ks], ao);
      }
    }
    // elementwise layer 0 + write h0(t) -> hA0[cur]
    #pragma unroll
    for (int j=0;j<4;++j){
      float r = sigm(aR[j]);
      float z = sigm(aZ[j]);
      float n = tanh_f(aNX[j] + r*aNH[j]);
      float h = n + z*(h0s[j]-n);
      h0s[j]=h;
      hA0[cur][wtile*512 + achunk(bg*4+j, kq_w)*8 + elem_w] = (_Float16)h;
    }
    __syncthreads();                                   // barrier 1

    // deferred out stores (drain hides at barrier 2)
    if (doout && col < OUTq){
      const int to = t - 2 + w;
      #pragma unroll
      for (int j=0;j<4;++j)
        out[(size_t)((b0 + bg*4 + j)*Tq + to)*OUTq + col] = ao[j] + bo_s;
    }
    // prefetch x(t+1) (drain hides at barrier 2)
    if (bg < 2){
      const int tn = (t+1 < Tq) ? t+1 : Tq-1;
      xfa = *(const float4*)&xrow[tn*INq + bg*8 + 0];
      xfb = *(const float4*)&xrow[tn*INq + bg*8 + 4];
    }

    // ---------------- phase B: layer-1 gates ----------------
    v4f cR  = {c1_r, c1_r, c1_r, c1_r};
    v4f cZ  = {c1_z, c1_z, c1_z, c1_z};
    v4f cNX = {c1_nx,c1_nx,c1_nx,c1_nx};
    v4f cNH = {c1_nh,c1_nh,c1_nh,c1_nh};
    #pragma unroll
    for (int ks=0;ks<4;++ks){
      v8h a0 = *(const v8h*)&hA0[cur][ks*512 + rch*8];
      v8h a1 = *(const v8h*)&hA1[prv][ks*512 + rch*8];
      cR  = MFMA(a0, Fih1[0][ks], cR);
      cZ  = MFMA(a0, Fih1[1][ks], cZ);
      cNX = MFMA(a0, Fih1[2][ks], cNX);
      cR  = MFMA(a1, Fhh1[0][ks], cR);
      cZ  = MFMA(a1, Fhh1[1][ks], cZ);
      cNH = MFMA(a1, Fhh1[2][ks], cNH);
    }
    #pragma unroll
    for (int j=0;j<4;++j){
      float r = sigm(cR[j]);
      float z = sigm(cZ[j]);
      float n = tanh_f(cNX[j] + r*cNH[j]);
      float h = n + z*(h1s[j]-n);
      h1s[j]=h;
      hA1[cur][wtile*512 + achunk(bg*4+j, kq_w)*8 + elem_w] = (_Float16)h;
    }
    __syncthreads();                                   // barrier 2
  }

  // epilogue: out(Tq-2) by wave0 from hA1[0], out(Tq-1) by wave1 from hA1[1]
  if (w < 2){
    const _Float16* hsrc = &hA1[w][0];
    v4f ao = {0.f,0.f,0.f,0.f};
    #pragma unroll
    for (int ks=0;ks<4;++ks){
      v8h a = *(const v8h*)&hsrc[ks*512 + rch*8];
      ao = MFMA(a, Fo[ks], ao);
    }
    if (col < OUTq){
      const int to = Tq - 2 + w;
      #pragma unroll
      for (int j=0;j<4;++j)
        out[(size_t)((b0 + bg*4 + j)*Tq + to)*OUTq + col] = ao[j] + bo_s;
    }
  }
}

extern "C" void kernel_launch(void* const* d_in, const int* in_sizes, int n_in,
                              void* d_out, int out_size, void* d_ws, size_t ws_size,
                              hipStream_t stream) {
  const float* x    = (const float*)d_in[0];
  const float* Wih0 = (const float*)d_in[1];
  const float* Whh0 = (const float*)d_in[2];
  const float* bih0 = (const float*)d_in[3];
  const float* bhh0 = (const float*)d_in[4];
  const float* Wih1 = (const float*)d_in[5];
  const float* Whh1 = (const float*)d_in[6];
  const float* bih1 = (const float*)d_in[7];
  const float* bhh1 = (const float*)d_in[8];
  const float* Wout = (const float*)d_in[9];
  const float* bo   = (const float*)d_in[10];
  gru2_kernel<<<dim3(32), dim3(512), 0, stream>>>(
      x, Wih0, Whh0, bih0, bhh0, Wih1, Whh1, bih1, bhh1, Wout, bo,
      (float*)d_out);
}